// Round 5
// baseline (436.014 us; speedup 1.0000x reference)
//
#include <hip/hip_runtime.h>
#include <cstddef>

#define N_NODES  100000
#define N_EDGES  640000
#define WIDTH    128
#define LAYERS   3
#define N_GRAPHS 64

#define SCAN_CHUNK 1024
#define NBLK ((N_NODES + SCAN_CHUNK - 1) / SCAN_CHUNK)  // 98

typedef __attribute__((ext_vector_type(8))) short bf16x8;
typedef __attribute__((ext_vector_type(4))) float f32x4;

__device__ __forceinline__ unsigned short f2bf(float f) {
  union { float f; unsigned u; } v; v.f = f;
  unsigned r = (v.u + 0x7fffu + ((v.u >> 16) & 1u)) >> 16;   // RNE
  return (unsigned short)r;
}
__device__ __forceinline__ float bf2f(unsigned short h) {
  union { float f; unsigned u; } v; v.u = ((unsigned)h) << 16;
  return v.f;
}

// ---------------- setup kernels ----------------

__global__ void k_init(int* __restrict__ counts, float* __restrict__ psum) {
  int i = blockIdx.x * blockDim.x + threadIdx.x;
  if (i < N_NODES) counts[i] = 0;
  if (i < N_GRAPHS * WIDTH) psum[i] = 0.0f;
}

__global__ void k_count(const int* __restrict__ col, int* __restrict__ counts) {
  int e = blockIdx.x * blockDim.x + threadIdx.x;
  if (e < N_EDGES) atomicAdd(&counts[col[e]], 1);
}

__global__ void k_scan1(const int* __restrict__ counts, int* __restrict__ bsum) {
  __shared__ int sd[256];
  int t = threadIdx.x;
  int base = blockIdx.x * SCAN_CHUNK;
  int s = 0;
  for (int j = t; j < SCAN_CHUNK; j += 256) {
    int idx = base + j;
    if (idx < N_NODES) s += counts[idx];
  }
  sd[t] = s; __syncthreads();
  for (int off = 128; off > 0; off >>= 1) {
    if (t < off) sd[t] += sd[t + off];
    __syncthreads();
  }
  if (t == 0) bsum[blockIdx.x] = sd[0];
}

__global__ void k_scan2(int* __restrict__ bsum) {
  if (threadIdx.x == 0 && blockIdx.x == 0) {
    int acc = 0;
    for (int i = 0; i < NBLK; i++) { int v = bsum[i]; bsum[i] = acc; acc += v; }
  }
}

__global__ void k_scan3(const int* __restrict__ counts, const int* __restrict__ bsum,
                        int* __restrict__ offs) {
  __shared__ int sd[256];
  int t = threadIdx.x;
  int base = blockIdx.x * SCAN_CHUNK;
  int idx0 = base + t * 4;
  int v0 = (idx0 + 0 < N_NODES) ? counts[idx0 + 0] : 0;
  int v1 = (idx0 + 1 < N_NODES) ? counts[idx0 + 1] : 0;
  int v2 = (idx0 + 2 < N_NODES) ? counts[idx0 + 2] : 0;
  int v3 = (idx0 + 3 < N_NODES) ? counts[idx0 + 3] : 0;
  int s = v0 + v1 + v2 + v3;
  sd[t] = s; __syncthreads();
  for (int off = 1; off < 256; off <<= 1) {
    int val = (t >= off) ? sd[t - off] : 0;
    __syncthreads();
    sd[t] += val;
    __syncthreads();
  }
  int excl = sd[t] - s + bsum[blockIdx.x];
  if (idx0 + 0 < N_NODES) offs[idx0 + 0] = excl; excl += v0;
  if (idx0 + 1 < N_NODES) offs[idx0 + 1] = excl; excl += v1;
  if (idx0 + 2 < N_NODES) offs[idx0 + 2] = excl; excl += v2;
  if (idx0 + 3 < N_NODES) offs[idx0 + 3] = excl; excl += v3;
  if (blockIdx.x == NBLK - 1 && t == 255) offs[N_NODES] = excl;  // == N_EDGES
}

__global__ void k_copy(const int* __restrict__ offs, int* __restrict__ cursor) {
  int i = blockIdx.x * blockDim.x + threadIdx.x;
  if (i < N_NODES) cursor[i] = offs[i];
}

__global__ void k_fill(const int* __restrict__ row, const int* __restrict__ col,
                       const float* __restrict__ ew, int* __restrict__ cursor,
                       int* __restrict__ csr_r, float* __restrict__ csr_w) {
  int e = blockIdx.x * blockDim.x + threadIdx.x;
  if (e < N_EDGES) {
    int c = col[e];
    int slot = atomicAdd(&cursor[c], 1);
    csr_r[slot] = row[e];
    csr_w[slot] = ew[e];
  }
}

// deg[v] = 2 (self loop) + sum of incoming edge weights; dinv = 1/sqrt(deg)
__global__ void k_dinv(const int* __restrict__ offs, const float* __restrict__ csr_w,
                       float* __restrict__ dinv) {
  int v = blockIdx.x * blockDim.x + threadIdx.x;
  if (v < N_NODES) {
    int s0 = offs[v], s1 = offs[v + 1];
    float d = 2.0f;
    for (int s = s0; s < s1; s++) d += csr_w[s];
    dinv[v] = (d > 0.0f) ? 1.0f / sqrtf(d) : 0.0f;
  }
}

// csr_w[s] <- dinv[row] * w * dinv[col]
__global__ void k_norm(const int* __restrict__ offs, const int* __restrict__ csr_r,
                       const float* __restrict__ dinv, float* __restrict__ csr_w) {
  int v = blockIdx.x * blockDim.x + threadIdx.x;
  if (v < N_NODES) {
    float dv = dinv[v];
    int s0 = offs[v], s1 = offs[v + 1];
    for (int s = s0; s < s1; s++) csr_w[s] = dinv[csr_r[s]] * csr_w[s] * dv;
  }
}

// Convert W[l] (f32, [k][n]) -> transposed bf16 hi/lo ([n][k]) via LDS.
__global__ __launch_bounds__(256) void k_wconv(
    const float* __restrict__ Ws, unsigned short* __restrict__ wt_hi,
    unsigned short* __restrict__ wt_lo) {
  __shared__ float Wl[WIDTH * WIDTH];   // 64 KB
  int l = blockIdx.x;
  int t = threadIdx.x;
  const float4* Wg = (const float4*)(Ws + l * WIDTH * WIDTH);
#pragma unroll
  for (int i = 0; i < 16; i++) {
    int idx = t + i * 256;              // 0..4095 float4
    *(float4*)&Wl[idx * 4] = Wg[idx];
  }
  __syncthreads();
  int n = t >> 1;
  int kh = (t & 1) * 64;
  unsigned short* dh = wt_hi + l * WIDTH * WIDTH + n * WIDTH + kh;
  unsigned short* dl = wt_lo + l * WIDTH * WIDTH + n * WIDTH + kh;
#pragma unroll
  for (int i = 0; i < 16; i++) {
    ushort4 h4, l4;
#pragma unroll
    for (int j = 0; j < 4; j++) {
      float f = Wl[(kh + i * 4 + j) * WIDTH + n];
      unsigned short hi = f2bf(f);
      unsigned short lo = f2bf(f - bf2f(hi));
      ((unsigned short*)&h4)[j] = hi;
      ((unsigned short*)&l4)[j] = lo;
    }
    *(ushort4*)(dh + i * 4) = h4;
    *(ushort4*)(dl + i * 4) = l4;
  }
}

// One-time: x f32 -> split-bf16 planes
__global__ void k_xconv(const float* __restrict__ x,
                        unsigned short* __restrict__ xh,
                        unsigned short* __restrict__ xl) {
  const int total = N_NODES * 32;   // float4 count
  for (int i = blockIdx.x * blockDim.x + threadIdx.x; i < total;
       i += gridDim.x * blockDim.x) {
    float4 v = ((const float4*)x)[i];
    const float* vf = (const float*)&v;
    ushort4 h4, l4;
#pragma unroll
    for (int j = 0; j < 4; j++) {
      unsigned short hi = f2bf(vf[j]);
      ((unsigned short*)&h4)[j] = hi;
      ((unsigned short*)&l4)[j] = f2bf(vf[j] - bf2f(hi));
    }
    ((ushort4*)xh)[i] = h4;
    ((ushort4*)xl)[i] = l4;
  }
}

// ---------------- MFMA GEMM: h = x @ W, no LDS ----------------
// 4 waves (2x2), wave = 64x64 via 4x4 16x16x32 tiles, K=128 in 4 steps.
// ALL A-plane fragments (HBM-streaming operand) are loaded up front: 32
// outstanding 16B loads/wave covers ~900cy HBM latency. B (W hi/lo) is
// L2-resident after warmup; loaded just-in-time inside the K-loop where
// the 48 MFMAs/step (~240cy) hide the ~200cy L2 latency.

#define GM_THREADS 256
#define GM_BLOCKS ((N_NODES + 127) / 128)   // 782

__global__ __launch_bounds__(GM_THREADS, 2) void k_gemm(
    const unsigned short* __restrict__ xh, const unsigned short* __restrict__ xl,
    const unsigned short* __restrict__ wh, const unsigned short* __restrict__ wl,
    float* __restrict__ h) {
  int t = threadIdx.x;
  int lane = t & 63;
  int wave = t >> 6;
  int wm = (wave >> 1) * 64;
  int wn = (wave & 1) * 64;
  int rbase = blockIdx.x * 128;
  int cl = lane & 15;
  int g = lane >> 4;          // k-chunk within fragment

  const unsigned short* ah_p = xh + (size_t)(rbase + wm + cl) * WIDTH + g * 8;
  const unsigned short* al_p = xl + (size_t)(rbase + wm + cl) * WIDTH + g * 8;
  const unsigned short* bh_p = wh + (wn + cl) * WIDTH + g * 8;
  const unsigned short* bl_p = wl + (wn + cl) * WIDTH + g * 8;

  // ---- all A fragments up front: 32 loads in flight per wave ----
  bf16x8 Ah[4][4], Al[4][4];           // [ks][mt], 128 VGPR
#pragma unroll
  for (int ks = 0; ks < 4; ks++)
#pragma unroll
    for (int mt = 0; mt < 4; mt++) {
      Ah[ks][mt] = *(const bf16x8*)(ah_p + mt * 16 * WIDTH + ks * 32);
      Al[ks][mt] = *(const bf16x8*)(al_p + mt * 16 * WIDTH + ks * 32);
    }

  f32x4 acc[4][4];
#pragma unroll
  for (int i = 0; i < 4; i++)
#pragma unroll
    for (int j = 0; j < 4; j++) acc[i][j] = (f32x4){0.f, 0.f, 0.f, 0.f};

#pragma unroll
  for (int ks = 0; ks < 4; ks++) {
    bf16x8 Bh[4], Bl[4];
#pragma unroll
    for (int nt = 0; nt < 4; nt++) {
      Bh[nt] = *(const bf16x8*)(bh_p + nt * 16 * WIDTH + ks * 32);
      Bl[nt] = *(const bf16x8*)(bl_p + nt * 16 * WIDTH + ks * 32);
    }
#pragma unroll
    for (int nt = 0; nt < 4; nt++)
#pragma unroll
      for (int mt = 0; mt < 4; mt++) {
        acc[mt][nt] = __builtin_amdgcn_mfma_f32_16x16x32_bf16(Ah[ks][mt], Bh[nt], acc[mt][nt], 0, 0, 0);
        acc[mt][nt] = __builtin_amdgcn_mfma_f32_16x16x32_bf16(Ah[ks][mt], Bl[nt], acc[mt][nt], 0, 0, 0);
        acc[mt][nt] = __builtin_amdgcn_mfma_f32_16x16x32_bf16(Al[ks][mt], Bh[nt], acc[mt][nt], 0, 0, 0);
      }
  }

  // C layout: col = lane&15, row = (lane>>4)*4 + j
  int gq = lane >> 4;
#pragma unroll
  for (int mt = 0; mt < 4; mt++) {
    int row0 = rbase + wm + mt * 16 + gq * 4;
#pragma unroll
    for (int nt = 0; nt < 4; nt++) {
      int col = wn + nt * 16 + cl;
#pragma unroll
      for (int j = 0; j < 4; j++) {
        int row = row0 + j;
        if (row < N_NODES) h[(size_t)row * WIDTH + col] = acc[mt][nt][j];
      }
    }
  }
}

// x_out[v] = 2*dinv[v]^2*h[v] + sum_in norm*h[row] + bias  -> split-bf16 planes
#define AGG_NPB 4
__global__ __launch_bounds__(256) void k_agg(
    const float* __restrict__ h, const int* __restrict__ offs,
    const int* __restrict__ csr_r, const float* __restrict__ csr_n,
    const float* __restrict__ dinv, const float* __restrict__ bias,
    unsigned short* __restrict__ xoh, unsigned short* __restrict__ xol) {
  int wave = threadIdx.x >> 6;
  int lane = threadIdx.x & 63;
  int v = blockIdx.x * AGG_NPB + wave;
  if (v >= N_NODES) return;
  int half = lane >> 5;   // edge parity within a pair
  int q = lane & 31;      // float4 slot within the 128-wide row
  const float4* h4 = (const float4*)h;

  float4 a0 = {0,0,0,0}, a1 = {0,0,0,0}, a2 = {0,0,0,0}, a3 = {0,0,0,0};
  int s0 = offs[v], s1 = offs[v + 1];

  for (int c0 = s0; c0 < s1; c0 += 64) {
    int cc = min(64, s1 - c0);
    int   si = (lane < cc) ? csr_r[c0 + lane] : 0;
    float swv = (lane < cc) ? csr_n[c0 + lane] : 0.f;
    for (int base = 0; base < cc; base += 8) {
      int e0 = base + half;
      int e1 = base + 2 + half;
      int e2 = base + 4 + half;
      int e3 = base + 6 + half;
      float w0 = __shfl(swv, e0); int i0 = __shfl(si, e0);
      float w1 = __shfl(swv, e1); int i1 = __shfl(si, e1);
      float w2 = __shfl(swv, e2); int i2 = __shfl(si, e2);
      float w3 = __shfl(swv, e3); int i3 = __shfl(si, e3);
      float4 v0 = h4[(size_t)i0 * 32 + q];
      float4 v1 = h4[(size_t)i1 * 32 + q];
      float4 v2 = h4[(size_t)i2 * 32 + q];
      float4 v3 = h4[(size_t)i3 * 32 + q];
      a0.x += w0 * v0.x; a0.y += w0 * v0.y; a0.z += w0 * v0.z; a0.w += w0 * v0.w;
      a1.x += w1 * v1.x; a1.y += w1 * v1.y; a1.z += w1 * v1.z; a1.w += w1 * v1.w;
      a2.x += w2 * v2.x; a2.y += w2 * v2.y; a2.z += w2 * v2.z; a2.w += w2 * v2.w;
      a3.x += w3 * v3.x; a3.y += w3 * v3.y; a3.z += w3 * v3.z; a3.w += w3 * v3.w;
    }
  }

  a0.x += a1.x + a2.x + a3.x;
  a0.y += a1.y + a2.y + a3.y;
  a0.z += a1.z + a2.z + a3.z;
  a0.w += a1.w + a2.w + a3.w;
  a0.x += __shfl_xor(a0.x, 32);
  a0.y += __shfl_xor(a0.y, 32);
  a0.z += __shfl_xor(a0.z, 32);
  a0.w += __shfl_xor(a0.w, 32);

  if (half == 0) {
    float dv = dinv[v];
    float sc = 2.0f * dv * dv;
    float4 hv = h4[(size_t)v * 32 + q];
    float4 bv = ((const float4*)bias)[q];
    float r[4];
    r[0] = a0.x + sc * hv.x + bv.x;
    r[1] = a0.y + sc * hv.y + bv.y;
    r[2] = a0.z + sc * hv.z + bv.z;
    r[3] = a0.w + sc * hv.w + bv.w;
    ushort4 h4o, l4o;
#pragma unroll
    for (int j = 0; j < 4; j++) {
      unsigned short hi = f2bf(r[j]);
      ((unsigned short*)&h4o)[j] = hi;
      ((unsigned short*)&l4o)[j] = f2bf(r[j] - bf2f(hi));
    }
    ((ushort4*)xoh)[(size_t)v * 32 + q] = h4o;
    ((ushort4*)xol)[(size_t)v * 32 + q] = l4o;
  }
}

// ---------------- pooling (reads split-bf16 planes) ----------------

#define POOL_CH 64
__global__ __launch_bounds__(WIDTH) void k_pool(
    const unsigned short* __restrict__ xh, const unsigned short* __restrict__ xl,
    const int* __restrict__ batch, float* __restrict__ psum) {
  int t = threadIdx.x;
  int start = blockIdx.x * POOL_CH;
  if (start >= N_NODES) return;
  int end = min(start + POOL_CH, N_NODES);
  float acc = 0.f;
  int g = batch[start];
  for (int n = start; n < end; n++) {
    int gn = batch[n];
    if (gn != g) {
      atomicAdd(&psum[g * WIDTH + t], acc);
      acc = 0.f;
      g = gn;
    }
    size_t idx = (size_t)n * WIDTH + t;
    acc += bf2f(xh[idx]) + bf2f(xl[idx]);
  }
  atomicAdd(&psum[g * WIDTH + t], acc);
}

__global__ void k_final(const float* __restrict__ psum, const int* __restrict__ batch,
                        float* __restrict__ out) {
  int g = blockIdx.x;
  int t = threadIdx.x;
  int lo = 0, hi = N_NODES;
  while (lo < hi) { int m = (lo + hi) >> 1; if (batch[m] < g) lo = m + 1; else hi = m; }
  int lb = lo;
  lo = 0; hi = N_NODES;
  while (lo < hi) { int m = (lo + hi) >> 1; if (batch[m] < g + 1) lo = m + 1; else hi = m; }
  int cnt = lo - lb;
  out[g * WIDTH + t] = psum[g * WIDTH + t] / fmaxf((float)cnt, 1.0f);
}

// ---------------- launch ----------------

extern "C" void kernel_launch(void* const* d_in, const int* in_sizes, int n_in,
                              void* d_out, int out_size, void* d_ws, size_t ws_size,
                              hipStream_t stream) {
  const float* x   = (const float*)d_in[0];
  const int* row   = (const int*)d_in[1];         // edge_index[0]
  const int* col   = row + N_EDGES;               // edge_index[1]
  const float* ew  = (const float*)d_in[2];
  const int* batch = (const int*)d_in[3];
  const float* Ws  = (const float*)d_in[4];
  const float* bs  = (const float*)d_in[5];
  float* out = (float*)d_out;

  char* w = (char*)d_ws;
  float* dinv  = (float*)(w + 0);          // N
  int* counts  = (int*)(w + 400128);       // N (dead after scan3 -> reused for Wt)
  unsigned short* wt_hi = (unsigned short*)(w + 400128);          // 3*128*128 bf16
  unsigned short* wt_lo = (unsigned short*)(w + 400128 + 98304);  // 3*128*128 bf16
  int* offs    = (int*)(w + 800256);       // N+1
  int* cursor  = (int*)(w + 1200384);      // N
  int* bsum    = (int*)(w + 1600512);      // NBLK
  int* csr_r   = (int*)(w + 1601024);      // E
  float* csr_n = (float*)(w + 4161024);    // E
  float* psum  = (float*)(w + 6721024);    // 64*128
  unsigned short* x_hi = (unsigned short*)(w + 6753792);   // N*128 bf16, ends 32353792
  unsigned short* x_lo = (unsigned short*)(w + 32353792);  // N*128 bf16, ends 57953792
  float* hbuf  = (float*)(w + 57953792);   // N*128 f32   (total ~109.2 MB)

  int nb_n = (N_NODES + 255) / 256;
  int nb_e = (N_EDGES + 255) / 256;

  k_init <<<nb_n, 256, 0, stream>>>(counts, psum);
  k_count<<<nb_e, 256, 0, stream>>>(col, counts);
  k_scan1<<<NBLK, 256, 0, stream>>>(counts, bsum);
  k_scan2<<<1, 64, 0, stream>>>(bsum);
  k_scan3<<<NBLK, 256, 0, stream>>>(counts, bsum, offs);
  k_copy <<<nb_n, 256, 0, stream>>>(offs, cursor);
  k_wconv<<<LAYERS, 256, 0, stream>>>(Ws, wt_hi, wt_lo);   // counts dead now
  k_fill <<<nb_e, 256, 0, stream>>>(row, col, ew, cursor, csr_r, csr_n);
  k_dinv <<<nb_n, 256, 0, stream>>>(offs, csr_n, dinv);
  k_norm <<<nb_n, 256, 0, stream>>>(offs, csr_r, dinv, csr_n);
  k_xconv<<<2048, 256, 0, stream>>>(x, x_hi, x_lo);

  for (int l = 0; l < LAYERS; l++) {
    k_gemm<<<GM_BLOCKS, GM_THREADS, 0, stream>>>(
        x_hi, x_lo, wt_hi + l * WIDTH * WIDTH, wt_lo + l * WIDTH * WIDTH, hbuf);
    k_agg<<<(N_NODES + AGG_NPB - 1) / AGG_NPB, 256, 0, stream>>>(
        hbuf, offs, csr_r, csr_n, dinv, bs + l * WIDTH, x_hi, x_lo);
  }

  k_pool <<<(N_NODES + POOL_CH - 1) / POOL_CH, WIDTH, 0, stream>>>(x_hi, x_lo, batch, psum);
  k_final<<<N_GRAPHS, WIDTH, 0, stream>>>(psum, batch, out);
}

// Round 6
// 418.988 us; speedup vs baseline: 1.0406x; 1.0406x over previous
//
#include <hip/hip_runtime.h>
#include <cstddef>

#define N_NODES  100000
#define N_EDGES  640000
#define WIDTH    128
#define LAYERS   3
#define N_GRAPHS 64

#define SCAN_CHUNK 1024
#define NBLK ((N_NODES + SCAN_CHUNK - 1) / SCAN_CHUNK)  // 98

typedef __attribute__((ext_vector_type(8))) short bf16x8;
typedef __attribute__((ext_vector_type(4))) float f32x4;

__device__ __forceinline__ unsigned short f2bf(float f) {
  union { float f; unsigned u; } v; v.f = f;
  unsigned r = (v.u + 0x7fffu + ((v.u >> 16) & 1u)) >> 16;   // RNE
  return (unsigned short)r;
}
__device__ __forceinline__ float bf2f(unsigned short h) {
  union { float f; unsigned u; } v; v.u = ((unsigned)h) << 16;
  return v.f;
}

#define GLOAD_LDS16(gsrc, ldst) \
  __builtin_amdgcn_global_load_lds( \
      (const __attribute__((address_space(1))) unsigned*)(gsrc), \
      (__attribute__((address_space(3))) unsigned*)(ldst), 16, 0, 0)

// ---------------- setup kernels ----------------

__global__ void k_init(int* __restrict__ counts, float* __restrict__ psum) {
  int i = blockIdx.x * blockDim.x + threadIdx.x;
  if (i < N_NODES) counts[i] = 0;
  if (i < N_GRAPHS * WIDTH) psum[i] = 0.0f;
}

__global__ void k_count(const int* __restrict__ col, int* __restrict__ counts) {
  int e = blockIdx.x * blockDim.x + threadIdx.x;
  if (e < N_EDGES) atomicAdd(&counts[col[e]], 1);
}

__global__ void k_scan1(const int* __restrict__ counts, int* __restrict__ bsum) {
  __shared__ int sd[256];
  int t = threadIdx.x;
  int base = blockIdx.x * SCAN_CHUNK;
  int s = 0;
  for (int j = t; j < SCAN_CHUNK; j += 256) {
    int idx = base + j;
    if (idx < N_NODES) s += counts[idx];
  }
  sd[t] = s; __syncthreads();
  for (int off = 128; off > 0; off >>= 1) {
    if (t < off) sd[t] += sd[t + off];
    __syncthreads();
  }
  if (t == 0) bsum[blockIdx.x] = sd[0];
}

__global__ void k_scan2(int* __restrict__ bsum) {
  if (threadIdx.x == 0 && blockIdx.x == 0) {
    int acc = 0;
    for (int i = 0; i < NBLK; i++) { int v = bsum[i]; bsum[i] = acc; acc += v; }
  }
}

// also writes cursor (merged old k_copy)
__global__ void k_scan3(const int* __restrict__ counts, const int* __restrict__ bsum,
                        int* __restrict__ offs, int* __restrict__ cursor) {
  __shared__ int sd[256];
  int t = threadIdx.x;
  int base = blockIdx.x * SCAN_CHUNK;
  int idx0 = base + t * 4;
  int v0 = (idx0 + 0 < N_NODES) ? counts[idx0 + 0] : 0;
  int v1 = (idx0 + 1 < N_NODES) ? counts[idx0 + 1] : 0;
  int v2 = (idx0 + 2 < N_NODES) ? counts[idx0 + 2] : 0;
  int v3 = (idx0 + 3 < N_NODES) ? counts[idx0 + 3] : 0;
  int s = v0 + v1 + v2 + v3;
  sd[t] = s; __syncthreads();
  for (int off = 1; off < 256; off <<= 1) {
    int val = (t >= off) ? sd[t - off] : 0;
    __syncthreads();
    sd[t] += val;
    __syncthreads();
  }
  int excl = sd[t] - s + bsum[blockIdx.x];
  int e0 = excl;
  if (idx0 + 0 < N_NODES) { offs[idx0 + 0] = e0; cursor[idx0 + 0] = e0; } e0 += v0;
  if (idx0 + 1 < N_NODES) { offs[idx0 + 1] = e0; cursor[idx0 + 1] = e0; } e0 += v1;
  if (idx0 + 2 < N_NODES) { offs[idx0 + 2] = e0; cursor[idx0 + 2] = e0; } e0 += v2;
  if (idx0 + 3 < N_NODES) { offs[idx0 + 3] = e0; cursor[idx0 + 3] = e0; } e0 += v3;
  if (blockIdx.x == NBLK - 1 && t == 255) offs[N_NODES] = e0;  // == N_EDGES
}

__global__ void k_fill(const int* __restrict__ row, const int* __restrict__ col,
                       const float* __restrict__ ew, int* __restrict__ cursor,
                       int* __restrict__ csr_r, float* __restrict__ csr_w) {
  int e = blockIdx.x * blockDim.x + threadIdx.x;
  if (e < N_EDGES) {
    int c = col[e];
    int slot = atomicAdd(&cursor[c], 1);
    csr_r[slot] = row[e];
    csr_w[slot] = ew[e];
  }
}

// deg[v] = 2 (self loop) + sum of incoming edge weights; dinv = 1/sqrt(deg)
__global__ void k_dinv(const int* __restrict__ offs, const float* __restrict__ csr_w,
                       float* __restrict__ dinv) {
  int v = blockIdx.x * blockDim.x + threadIdx.x;
  if (v < N_NODES) {
    int s0 = offs[v], s1 = offs[v + 1];
    float d = 2.0f;
    for (int s = s0; s < s1; s++) d += csr_w[s];
    dinv[v] = (d > 0.0f) ? 1.0f / sqrtf(d) : 0.0f;
  }
}

// csr_w[s] <- dinv[row] * w * dinv[col]
__global__ void k_norm(const int* __restrict__ offs, const int* __restrict__ csr_r,
                       const float* __restrict__ dinv, float* __restrict__ csr_w) {
  int v = blockIdx.x * blockDim.x + threadIdx.x;
  if (v < N_NODES) {
    float dv = dinv[v];
    int s0 = offs[v], s1 = offs[v + 1];
    for (int s = s0; s < s1; s++) csr_w[s] = dinv[csr_r[s]] * csr_w[s] * dv;
  }
}

// Convert W[l] (f32, [k][n]) -> transposed bf16 hi/lo ([n][k]) via LDS.
__global__ __launch_bounds__(256) void k_wconv(
    const float* __restrict__ Ws, unsigned short* __restrict__ wt_hi,
    unsigned short* __restrict__ wt_lo) {
  __shared__ float Wl[WIDTH * WIDTH];   // 64 KB
  int l = blockIdx.x;
  int t = threadIdx.x;
  const float4* Wg = (const float4*)(Ws + l * WIDTH * WIDTH);
#pragma unroll
  for (int i = 0; i < 16; i++) {
    int idx = t + i * 256;              // 0..4095 float4
    *(float4*)&Wl[idx * 4] = Wg[idx];
  }
  __syncthreads();
  int n = t >> 1;
  int kh = (t & 1) * 64;
  unsigned short* dh = wt_hi + l * WIDTH * WIDTH + n * WIDTH + kh;
  unsigned short* dl = wt_lo + l * WIDTH * WIDTH + n * WIDTH + kh;
#pragma unroll
  for (int i = 0; i < 16; i++) {
    ushort4 h4, l4;
#pragma unroll
    for (int j = 0; j < 4; j++) {
      float f = Wl[(kh + i * 4 + j) * WIDTH + n];
      unsigned short hi = f2bf(f);
      unsigned short lo = f2bf(f - bf2f(hi));
      ((unsigned short*)&h4)[j] = hi;
      ((unsigned short*)&l4)[j] = lo;
    }
    *(ushort4*)(dh + i * 4) = h4;
    *(ushort4*)(dl + i * 4) = l4;
  }
}

// One-time: x f32 -> split-bf16 planes
__global__ void k_xconv(const float* __restrict__ x,
                        unsigned short* __restrict__ xh,
                        unsigned short* __restrict__ xl) {
  const int total = N_NODES * 32;   // float4 count
  for (int i = blockIdx.x * blockDim.x + threadIdx.x; i < total;
       i += gridDim.x * blockDim.x) {
    float4 v = ((const float4*)x)[i];
    const float* vf = (const float*)&v;
    ushort4 h4, l4;
#pragma unroll
    for (int j = 0; j < 4; j++) {
      unsigned short hi = f2bf(vf[j]);
      ((unsigned short*)&h4)[j] = hi;
      ((unsigned short*)&l4)[j] = f2bf(vf[j] - bf2f(hi));
    }
    ((ushort4*)xh)[i] = h4;
    ((ushort4*)xl)[i] = l4;
  }
}

// ---------------- MFMA GEMM: h = x @ W ----------------
// m97 pattern: A hi/lo tile staged to LDS via global_load_lds width=16
// (linear LDS dest, XOR-pre-swizzled global SOURCE, XOR-swizzled ds_read:
// swz byte-in-row ^= (row&7)<<4, an involution). B (W hi/lo, 64KB, L2-hot)
// read directly from global inside the K-loop where MFMAs cover L2 latency.
// 4 waves (2x2), wave = 64x64 via 4x4 16x16x32 tiles, K=128 in 4 ks-steps.

#define GM_THREADS 256
#define GM_BLOCKS ((N_NODES + 127) / 128)   // 782

__global__ __launch_bounds__(GM_THREADS) void k_gemm(
    const unsigned short* __restrict__ xh, const unsigned short* __restrict__ xl,
    const unsigned short* __restrict__ wh, const unsigned short* __restrict__ wl,
    float* __restrict__ h) {
  __shared__ __align__(16) unsigned short Ah_l[128 * 128];  // 32 KB
  __shared__ __align__(16) unsigned short Al_l[128 * 128];  // 32 KB

  int t = threadIdx.x;
  int lane = t & 63;
  int wave = t >> 6;
  int rbase = blockIdx.x * 128;

  // ---- stage A planes: 8 global_load_lds dwordx4 per plane per thread ----
  // linear byte off in tile = i*4096 + t*16 ; row = off>>8, byte = off&255
  // source byte-in-row pre-swizzled so that swizzled READS return true data
#pragma unroll
  for (int i = 0; i < 8; i++) {
    int off = i * 4096 + t * 16;
    int r = off >> 8;
    int b = off & 255;
    int srcb = b ^ ((r & 7) << 4);
    const char* gh = (const char*)xh + (size_t)(rbase + r) * 256 + srcb;
    const char* gl = (const char*)xl + (size_t)(rbase + r) * 256 + srcb;
    char* dh = (char*)Ah_l + i * 4096 + wave * 1024;   // wave-uniform base
    char* dl = (char*)Al_l + i * 4096 + wave * 1024;
    GLOAD_LDS16(gh, dh);
    GLOAD_LDS16(gl, dl);
  }
  asm volatile("s_waitcnt vmcnt(0)" ::: "memory");
  __syncthreads();

  int wm = (wave >> 1) * 64;
  int wn = (wave & 1) * 64;
  int cl = lane & 15;
  int g = lane >> 4;          // k-chunk within fragment

  const unsigned short* bh_p = wh + (wn + cl) * WIDTH + g * 8;
  const unsigned short* bl_p = wl + (wn + cl) * WIDTH + g * 8;

  f32x4 acc[4][4];
#pragma unroll
  for (int i = 0; i < 4; i++)
#pragma unroll
    for (int j = 0; j < 4; j++) acc[i][j] = (f32x4){0.f, 0.f, 0.f, 0.f};

#pragma unroll
  for (int ks = 0; ks < 4; ks++) {
    bf16x8 Bh[4], Bl[4];
#pragma unroll
    for (int nt = 0; nt < 4; nt++) {
      Bh[nt] = *(const bf16x8*)(bh_p + nt * 16 * WIDTH + ks * 32);
      Bl[nt] = *(const bf16x8*)(bl_p + nt * 16 * WIDTH + ks * 32);
    }
    bf16x8 Ah[4], Al[4];
#pragma unroll
    for (int mt = 0; mt < 4; mt++) {
      int R = wm + mt * 16 + cl;
      int ofs = R * 256 + ((ks * 64 + g * 16) ^ ((R & 7) << 4));
      Ah[mt] = *(const bf16x8*)((const char*)Ah_l + ofs);
      Al[mt] = *(const bf16x8*)((const char*)Al_l + ofs);
    }
#pragma unroll
    for (int nt = 0; nt < 4; nt++)
#pragma unroll
      for (int mt = 0; mt < 4; mt++) {
        acc[mt][nt] = __builtin_amdgcn_mfma_f32_16x16x32_bf16(Ah[mt], Bh[nt], acc[mt][nt], 0, 0, 0);
        acc[mt][nt] = __builtin_amdgcn_mfma_f32_16x16x32_bf16(Ah[mt], Bl[nt], acc[mt][nt], 0, 0, 0);
        acc[mt][nt] = __builtin_amdgcn_mfma_f32_16x16x32_bf16(Al[mt], Bh[nt], acc[mt][nt], 0, 0, 0);
      }
  }

  // C layout: col = lane&15, row = (lane>>4)*4 + j
  int gq = lane >> 4;
#pragma unroll
  for (int mt = 0; mt < 4; mt++) {
    int row0 = rbase + wm + mt * 16 + gq * 4;
#pragma unroll
    for (int nt = 0; nt < 4; nt++) {
      int col = wn + nt * 16 + cl;
#pragma unroll
      for (int j = 0; j < 4; j++) {
        int row = row0 + j;
        if (row < N_NODES) h[(size_t)row * WIDTH + col] = acc[mt][nt][j];
      }
    }
  }
}

// x_out[v] = 2*dinv[v]^2*h[v] + sum_in norm*h[row] + bias  -> split-bf16 planes
#define AGG_NPB 4
__global__ __launch_bounds__(256) void k_agg(
    const float* __restrict__ h, const int* __restrict__ offs,
    const int* __restrict__ csr_r, const float* __restrict__ csr_n,
    const float* __restrict__ dinv, const float* __restrict__ bias,
    unsigned short* __restrict__ xoh, unsigned short* __restrict__ xol) {
  int wave = threadIdx.x >> 6;
  int lane = threadIdx.x & 63;
  int v = blockIdx.x * AGG_NPB + wave;
  if (v >= N_NODES) return;
  int half = lane >> 5;   // edge parity within a pair
  int q = lane & 31;      // float4 slot within the 128-wide row
  const float4* h4 = (const float4*)h;

  float4 a0 = {0,0,0,0}, a1 = {0,0,0,0}, a2 = {0,0,0,0}, a3 = {0,0,0,0};
  int s0 = offs[v], s1 = offs[v + 1];

  for (int c0 = s0; c0 < s1; c0 += 64) {
    int cc = min(64, s1 - c0);
    int   si = (lane < cc) ? csr_r[c0 + lane] : 0;
    float swv = (lane < cc) ? csr_n[c0 + lane] : 0.f;
    for (int base = 0; base < cc; base += 8) {
      int e0 = base + half;
      int e1 = base + 2 + half;
      int e2 = base + 4 + half;
      int e3 = base + 6 + half;
      float w0 = __shfl(swv, e0); int i0 = __shfl(si, e0);
      float w1 = __shfl(swv, e1); int i1 = __shfl(si, e1);
      float w2 = __shfl(swv, e2); int i2 = __shfl(si, e2);
      float w3 = __shfl(swv, e3); int i3 = __shfl(si, e3);
      float4 v0 = h4[(size_t)i0 * 32 + q];
      float4 v1 = h4[(size_t)i1 * 32 + q];
      float4 v2 = h4[(size_t)i2 * 32 + q];
      float4 v3 = h4[(size_t)i3 * 32 + q];
      a0.x += w0 * v0.x; a0.y += w0 * v0.y; a0.z += w0 * v0.z; a0.w += w0 * v0.w;
      a1.x += w1 * v1.x; a1.y += w1 * v1.y; a1.z += w1 * v1.z; a1.w += w1 * v1.w;
      a2.x += w2 * v2.x; a2.y += w2 * v2.y; a2.z += w2 * v2.z; a2.w += w2 * v2.w;
      a3.x += w3 * v3.x; a3.y += w3 * v3.y; a3.z += w3 * v3.z; a3.w += w3 * v3.w;
    }
  }

  a0.x += a1.x + a2.x + a3.x;
  a0.y += a1.y + a2.y + a3.y;
  a0.z += a1.z + a2.z + a3.z;
  a0.w += a1.w + a2.w + a3.w;
  a0.x += __shfl_xor(a0.x, 32);
  a0.y += __shfl_xor(a0.y, 32);
  a0.z += __shfl_xor(a0.z, 32);
  a0.w += __shfl_xor(a0.w, 32);

  if (half == 0) {
    float dv = dinv[v];
    float sc = 2.0f * dv * dv;
    float4 hv = h4[(size_t)v * 32 + q];
    float4 bv = ((const float4*)bias)[q];
    float r[4];
    r[0] = a0.x + sc * hv.x + bv.x;
    r[1] = a0.y + sc * hv.y + bv.y;
    r[2] = a0.z + sc * hv.z + bv.z;
    r[3] = a0.w + sc * hv.w + bv.w;
    ushort4 h4o, l4o;
#pragma unroll
    for (int j = 0; j < 4; j++) {
      unsigned short hi = f2bf(r[j]);
      ((unsigned short*)&h4o)[j] = hi;
      ((unsigned short*)&l4o)[j] = f2bf(r[j] - bf2f(hi));
    }
    ((ushort4*)xoh)[(size_t)v * 32 + q] = h4o;
    ((ushort4*)xol)[(size_t)v * 32 + q] = l4o;
  }
}

// ---------------- pooling (reads split-bf16 planes) ----------------

#define POOL_CH 64
__global__ __launch_bounds__(WIDTH) void k_pool(
    const unsigned short* __restrict__ xh, const unsigned short* __restrict__ xl,
    const int* __restrict__ batch, float* __restrict__ psum) {
  int t = threadIdx.x;
  int start = blockIdx.x * POOL_CH;
  if (start >= N_NODES) return;
  int end = min(start + POOL_CH, N_NODES);
  float acc = 0.f;
  int g = batch[start];
  for (int n = start; n < end; n++) {
    int gn = batch[n];
    if (gn != g) {
      atomicAdd(&psum[g * WIDTH + t], acc);
      acc = 0.f;
      g = gn;
    }
    size_t idx = (size_t)n * WIDTH + t;
    acc += bf2f(xh[idx]) + bf2f(xl[idx]);
  }
  atomicAdd(&psum[g * WIDTH + t], acc);
}

__global__ void k_final(const float* __restrict__ psum, const int* __restrict__ batch,
                        float* __restrict__ out) {
  int g = blockIdx.x;
  int t = threadIdx.x;
  int lo = 0, hi = N_NODES;
  while (lo < hi) { int m = (lo + hi) >> 1; if (batch[m] < g) lo = m + 1; else hi = m; }
  int lb = lo;
  lo = 0; hi = N_NODES;
  while (lo < hi) { int m = (lo + hi) >> 1; if (batch[m] < g + 1) lo = m + 1; else hi = m; }
  int cnt = lo - lb;
  out[g * WIDTH + t] = psum[g * WIDTH + t] / fmaxf((float)cnt, 1.0f);
}

// ---------------- launch ----------------

extern "C" void kernel_launch(void* const* d_in, const int* in_sizes, int n_in,
                              void* d_out, int out_size, void* d_ws, size_t ws_size,
                              hipStream_t stream) {
  const float* x   = (const float*)d_in[0];
  const int* row   = (const int*)d_in[1];         // edge_index[0]
  const int* col   = row + N_EDGES;               // edge_index[1]
  const float* ew  = (const float*)d_in[2];
  const int* batch = (const int*)d_in[3];
  const float* Ws  = (const float*)d_in[4];
  const float* bs  = (const float*)d_in[5];
  float* out = (float*)d_out;

  char* w = (char*)d_ws;
  float* dinv  = (float*)(w + 0);          // N
  int* counts  = (int*)(w + 400128);       // N (dead after scan3 -> reused for Wt)
  unsigned short* wt_hi = (unsigned short*)(w + 400128);          // 3*128*128 bf16
  unsigned short* wt_lo = (unsigned short*)(w + 400128 + 98304);  // 3*128*128 bf16
  int* offs    = (int*)(w + 800256);       // N+1
  int* cursor  = (int*)(w + 1200384);      // N
  int* bsum    = (int*)(w + 1600512);      // NBLK
  int* csr_r   = (int*)(w + 1601024);      // E
  float* csr_n = (float*)(w + 4161024);    // E
  float* psum  = (float*)(w + 6721024);    // 64*128
  unsigned short* x_hi = (unsigned short*)(w + 6753792);   // N*128 bf16, ends 32353792
  unsigned short* x_lo = (unsigned short*)(w + 32353792);  // N*128 bf16, ends 57953792
  float* hbuf  = (float*)(w + 57953792);   // N*128 f32   (total ~109.2 MB)

  int nb_n = (N_NODES + 255) / 256;
  int nb_e = (N_EDGES + 255) / 256;

  k_init <<<nb_n, 256, 0, stream>>>(counts, psum);
  k_count<<<nb_e, 256, 0, stream>>>(col, counts);
  k_scan1<<<NBLK, 256, 0, stream>>>(counts, bsum);
  k_scan2<<<1, 64, 0, stream>>>(bsum);
  k_scan3<<<NBLK, 256, 0, stream>>>(counts, bsum, offs, cursor);
  k_wconv<<<LAYERS, 256, 0, stream>>>(Ws, wt_hi, wt_lo);   // counts dead now
  k_fill <<<nb_e, 256, 0, stream>>>(row, col, ew, cursor, csr_r, csr_n);
  k_dinv <<<nb_n, 256, 0, stream>>>(offs, csr_n, dinv);
  k_norm <<<nb_n, 256, 0, stream>>>(offs, csr_r, dinv, csr_n);
  k_xconv<<<2048, 256, 0, stream>>>(x, x_hi, x_lo);

  for (int l = 0; l < LAYERS; l++) {
    k_gemm<<<GM_BLOCKS, GM_THREADS, 0, stream>>>(
        x_hi, x_lo, wt_hi + l * WIDTH * WIDTH, wt_lo + l * WIDTH * WIDTH, hbuf);
    k_agg<<<(N_NODES + AGG_NPB - 1) / AGG_NPB, 256, 0, stream>>>(
        hbuf, offs, csr_r, csr_n, dinv, bs + l * WIDTH, x_hi, x_lo);
  }

  k_pool <<<(N_NODES + POOL_CH - 1) / POOL_CH, WIDTH, 0, stream>>>(x_hi, x_lo, batch, psum);
  k_final<<<N_GRAPHS, WIDTH, 0, stream>>>(psum, batch, out);
}